// Round 6
// baseline (492.439 us; speedup 1.0000x reference)
//
#include <hip/hip_runtime.h>
#include <stdint.h>

typedef unsigned short ushort_t;
typedef short bf16x8 __attribute__((ext_vector_type(8)));
typedef float f32x4 __attribute__((ext_vector_type(4)));
typedef float f32x4v __attribute__((ext_vector_type(4)));

// ---------- helpers ----------
__device__ __forceinline__ ushort_t f2bf(float f) {
  unsigned int u = __builtin_bit_cast(unsigned int, f);
  u += 0x7fffu + ((u >> 16) & 1u);
  return (ushort_t)(u >> 16);
}
__device__ __forceinline__ float bf2f(ushort_t h) {
  unsigned int u = ((unsigned int)h) << 16;
  return __builtin_bit_cast(float, u);
}
__device__ __forceinline__ float exp2_hw(float x) {
  return __builtin_amdgcn_exp2f(x);  // v_exp_f32: D = 2^S0
}
__device__ __forceinline__ void load_lds16(const void* g, void* l) {
  __builtin_amdgcn_global_load_lds(
      (const __attribute__((address_space(1))) void*)g,
      (__attribute__((address_space(3))) void*)l, 16, 0, 0);
}

// ---------- x fp32 -> bf16 ----------
__global__ __launch_bounds__(256) void cvt_x_kernel(const float* __restrict__ x,
                                                    ushort_t* __restrict__ xb) {
  int i = blockIdx.x * 256 + threadIdx.x;  // each thread: 8 elems
  const f32x4v* xv = (const f32x4v*)x;
  f32x4v a = xv[2 * i], b = xv[2 * i + 1];
  bf16x8 o;
  o[0] = (short)f2bf(a[0]); o[1] = (short)f2bf(a[1]);
  o[2] = (short)f2bf(a[2]); o[3] = (short)f2bf(a[3]);
  o[4] = (short)f2bf(b[0]); o[5] = (short)f2bf(b[1]);
  o[6] = (short)f2bf(b[2]); o[7] = (short)f2bf(b[3]);
  ((bf16x8*)xb)[i] = o;
}

// ---------- weight fp32 [R][C] -> bf16 transposed [C][R] ----------
__global__ __launch_bounds__(256) void tr_cvt_kernel(const float* __restrict__ src,
                                                     ushort_t* __restrict__ dst,
                                                     int R, int C) {
  __shared__ float tile[64][65];
  int r0 = blockIdx.y * 64, c0 = blockIdx.x * 64;
  int t = threadIdx.x;
#pragma unroll
  for (int i = 0; i < 16; i++) {
    int idx = t + i * 256;
    int r = idx >> 6, c = idx & 63;
    tile[r][c] = src[(size_t)(r0 + r) * C + c0 + c];
  }
  __syncthreads();
#pragma unroll
  for (int i = 0; i < 16; i++) {
    int idx = t + i * 256;
    int cr = idx >> 6, cc = idx & 63;
    dst[(size_t)(c0 + cr) * R + r0 + cc] = f2bf(tile[cc][cr]);
  }
}

// ---------- RoPE in-place on C1 (Q cols 0..4095 get pre-scaled, K cols 4096..5119) ----------
// Q is pre-multiplied by 1/sqrt(128)*log2(e) so fattn can use exp2 directly on QK^T.
__global__ __launch_bounds__(256) void rope_kernel(ushort_t* __restrict__ C1,
                                                   const float* __restrict__ cosb,
                                                   const float* __restrict__ sinb) {
  int idx = blockIdx.x * 256 + threadIdx.x;  // 2048 * 640
  int s = idx / 640;
  int col0 = (idx % 640) * 8;
  int i0 = (col0 & 127) >> 1;
  const float qs = (col0 < 4096) ? 0.12753055296570565f : 1.0f;  // scale*log2e
  ushort_t* p = C1 + (size_t)s * 6144 + col0;
  bf16x8 v = *(const bf16x8*)p;
  bf16x8 o;
  const float* cr = cosb + s * 64 + i0;
  const float* sr = sinb + s * 64 + i0;
#pragma unroll
  for (int j = 0; j < 4; j++) {
    float tr = bf2f((ushort_t)v[2 * j]);
    float ti = bf2f((ushort_t)v[2 * j + 1]);
    float c = cr[j], sn = sr[j];
    o[2 * j] = (short)f2bf((tr * c - ti * sn) * qs);
    o[2 * j + 1] = (short)f2bf((tr * sn + ti * c) * qs);
  }
  *(bf16x8*)p = o;
}

// ---------- V part of C1 -> VT [1024][2048] (row = hk*128+d, col = s) ----------
__global__ __launch_bounds__(256) void trv_kernel(const ushort_t* __restrict__ C1,
                                                  ushort_t* __restrict__ VT) {
  __shared__ ushort_t tile[64][65];
  int c0 = blockIdx.x * 64;  // within 1024
  int r0 = blockIdx.y * 64;  // within 2048
  int t = threadIdx.x;
#pragma unroll
  for (int i = 0; i < 16; i++) {
    int idx = t + i * 256;
    int r = idx >> 6, c = idx & 63;
    tile[r][c] = C1[(size_t)(r0 + r) * 6144 + 5120 + c0 + c];
  }
  __syncthreads();
#pragma unroll
  for (int i = 0; i < 16; i++) {
    int idx = t + i * 256;
    int cr = idx >> 6, cc = idx & 63;
    VT[(size_t)(c0 + cr) * 2048 + r0 + cc] = tile[cc][cr];
  }
}

// ---------- GEMM: C[M][ldc] = A[M][K] * BT[N][K]^T  (m97 structure) ----------
template <typename OutT>
__global__ __launch_bounds__(256) void gemm128_kernel(const ushort_t* __restrict__ A,
                                                      const ushort_t* __restrict__ BT,
                                                      OutT* __restrict__ C,
                                                      int M, int N, int K, int ldc) {
  __shared__ ushort_t As[128 * 32];
  __shared__ ushort_t Bs[128 * 32];
  int brow = blockIdx.y * 128, bcol = blockIdx.x * 128;
  int tid = threadIdx.x, w = tid >> 6, lane = tid & 63;
  int wr = w >> 1, wc = w & 1;
  int lr = lane & 15, lk = lane >> 4;
  f32x4 acc[4][4] = {};

  int srow = lane >> 2;
  int scol = (lane & 3) * 8;
  const ushort_t* Ab = A + (size_t)brow * K + scol;
  const ushort_t* Bb = BT + (size_t)bcol * K + scol;

  for (int kt = 0; kt < K; kt += 32) {
#pragma unroll
    for (int i = 0; i < 2; i++) {
      int seg = w * 2 + i;
      int row = seg * 16 + srow;
      load_lds16(Ab + (size_t)row * K + kt, (char*)As + seg * 1024);
      load_lds16(Bb + (size_t)row * K + kt, (char*)Bs + seg * 1024);
    }
    __syncthreads();
    bf16x8 af[4], bfr[4];
#pragma unroll
    for (int m = 0; m < 4; m++)
      af[m] = *(const bf16x8*)&As[(wr * 64 + m * 16 + lr) * 32 + lk * 8];
#pragma unroll
    for (int n = 0; n < 4; n++)
      bfr[n] = *(const bf16x8*)&Bs[(wc * 64 + n * 16 + lr) * 32 + lk * 8];
#pragma unroll
    for (int m = 0; m < 4; m++)
#pragma unroll
      for (int n = 0; n < 4; n++)
        acc[m][n] = __builtin_amdgcn_mfma_f32_16x16x32_bf16(af[m], bfr[n], acc[m][n], 0, 0, 0);
    __syncthreads();
  }
#pragma unroll
  for (int m = 0; m < 4; m++)
#pragma unroll
    for (int n = 0; n < 4; n++) {
      int row = brow + wr * 64 + m * 16 + lk * 4;
      int col = bcol + wc * 64 + n * 16 + lr;
#pragma unroll
      for (int j = 0; j < 4; j++) {
        float v = acc[m][n][j];
        if constexpr (sizeof(OutT) == 2)
          C[(size_t)(row + j) * ldc + col] = (OutT)f2bf(v);
        else
          C[(size_t)(row + j) * ldc + col] = v;
      }
    }
}

// ---------- flash attention ----------
// grid (32 heads x 16 qtiles), 512 thr (8 waves), QBLK=128 (16 rows/wave), KVBLK=64.
// K double-buffered in LDS (global_load_lds, XOR-swizzled source — verified r1==r2).
// V read directly from VT via L2 (no LDS staging): LDS 50KB -> multi-block/CU.
// Grid x=h so all blocks of head h share XCD h%8 (K/V working set ~4MB = L2).
__global__ __launch_bounds__(512) void fattn_kernel(const ushort_t* __restrict__ C1,
                                                    const ushort_t* __restrict__ VT,
                                                    ushort_t* __restrict__ AO) {
  __shared__ ushort_t Ks[2][64 * 128];  // 16KB x2
  __shared__ ushort_t Pl[8][16][72];    // per-wave P tile (+8 pad), 18KB
  const int h = blockIdx.x, hk = h >> 2;
  const int qt = gridDim.y - 1 - blockIdx.y;  // longest blocks first
  const int q0 = qt * 128;
  const int tid = threadIdx.x, w = tid >> 6, lane = tid & 63;
  const int lr = lane & 15, lk = lane >> 4;

  const char* Kg0 = (const char*)(C1 + 4096 + (size_t)hk * 128);  // row stride 12288B
  const ushort_t* Vb0 = VT + (size_t)hk * 128 * 2048;             // row stride 2048 elems

  // stage K tile kt into buffer buf. LDS dest linear (seg base + lane*16);
  // global source pre-XOR'd so LDS chunk c of row r holds global chunk c^(r&7).
  auto stageK = [&](int kt, int buf) {
#pragma unroll
    for (int i = 0; i < 2; i++) {
      int seg = w * 2 + i;              // 16 segments of 1024B
      int row = seg * 4 + (lane >> 4);  // 4 rows (256B) per segment
      int srcb = ((lane & 15) << 4) ^ ((row & 7) << 4);
      load_lds16(Kg0 + (size_t)(kt * 64 + row) * 12288 + srcb,
                 (char*)&Ks[buf][0] + seg * 1024);
    }
  };

  // Q fragments in registers (A-operand: row=lr, d = kk*32 + lk*8 + j); Q pre-scaled.
  bf16x8 qf[4];
  {
    const ushort_t* qrow = C1 + (size_t)(q0 + w * 16 + lr) * 6144 + h * 128;
#pragma unroll
    for (int kk = 0; kk < 4; kk++) qf[kk] = *(const bf16x8*)(qrow + kk * 32 + lk * 8);
  }
  f32x4 o[8] = {};
  float mrow[4], ssum[4];
#pragma unroll
  for (int j = 0; j < 4; j++) { mrow[j] = -1e30f; ssum[j] = 0.f; }

  const int ktmax = 2 * qt + 1;
  stageK(0, 0);
  __syncthreads();

  for (int kt = 0; kt <= ktmax; kt++) {
    const int cur = kt & 1;
    if (kt < ktmax) stageK(kt + 1, cur ^ 1);  // async prefetch; hides under compute

    if (kt * 64 <= q0 + w * 16 + 15) {  // wave has unmasked work in this K-tile
      const char* Kb = (const char*)&Ks[cur][0];
      // S = Q K^T  (log2-domain: Q pre-scaled by 1/sqrt(128)*log2e)
      f32x4 s[4] = {};
#pragma unroll
      for (int kk = 0; kk < 4; kk++) {
#pragma unroll
        for (int n = 0; n < 4; n++) {
          int row = n * 16 + lr;
          bf16x8 kf = *(const bf16x8*)(Kb + row * 256 +
                                       ((lk * 16 + kk * 64) ^ ((row & 7) << 4)));
          s[n] = __builtin_amdgcn_mfma_f32_16x16x32_bf16(qf[kk], kf, s[n], 0, 0, 0);
        }
      }
      // causal mask + online softmax (base-2)
      const bool needmask = (kt * 64 + 63 > q0 + w * 16);
      float p[4][4], tm[4];
#pragma unroll
      for (int j = 0; j < 4; j++) tm[j] = -1e30f;
#pragma unroll
      for (int n = 0; n < 4; n++) {
        int k = kt * 64 + n * 16 + lr;
#pragma unroll
        for (int j = 0; j < 4; j++) {
          float v = s[n][j];
          if (needmask) {
            int q = q0 + w * 16 + lk * 4 + j;
            if (k > q) v = -1e30f;
          }
          p[n][j] = v;
          tm[j] = fmaxf(tm[j], v);
        }
      }
#pragma unroll
      for (int off = 1; off < 16; off <<= 1)
#pragma unroll
        for (int j = 0; j < 4; j++) tm[j] = fmaxf(tm[j], __shfl_xor(tm[j], off, 64));
      float corr[4], mnew[4];
#pragma unroll
      for (int j = 0; j < 4; j++) {
        mnew[j] = fmaxf(mrow[j], tm[j]);
        corr[j] = exp2_hw(mrow[j] - mnew[j]);
        mrow[j] = mnew[j];
      }
      float psum[4] = {0.f, 0.f, 0.f, 0.f};
#pragma unroll
      for (int n = 0; n < 4; n++)
#pragma unroll
        for (int j = 0; j < 4; j++) {
          float e = exp2_hw(p[n][j] - mnew[j]);
          p[n][j] = e;
          psum[j] += e;
        }
#pragma unroll
      for (int off = 1; off < 16; off <<= 1)
#pragma unroll
        for (int j = 0; j < 4; j++) psum[j] += __shfl_xor(psum[j], off, 64);
#pragma unroll
      for (int j = 0; j < 4; j++) ssum[j] = ssum[j] * corr[j] + psum[j];
      // T13: skip O-rescale when no row max grew (corr==1 exactly)
      if (corr[0] < 1.f || corr[1] < 1.f || corr[2] < 1.f || corr[3] < 1.f) {
#pragma unroll
        for (int g = 0; g < 8; g++)
#pragma unroll
          for (int j = 0; j < 4; j++) o[g][j] *= corr[j];
      }
      // P -> per-wave LDS (D-layout write, A-layout read); wave-local, lgkm drain only.
#pragma unroll
      for (int n = 0; n < 4; n++)
#pragma unroll
        for (int j = 0; j < 4; j++) Pl[w][lk * 4 + j][n * 16 + lr] = f2bf(p[n][j]);
      asm volatile("s_waitcnt lgkmcnt(0)" ::: "memory");
      // O += P V ; V fragments read directly from VT (L2)
      const ushort_t* Vt = Vb0 + kt * 64;
#pragma unroll
      for (int ks = 0; ks < 2; ks++) {
        bf16x8 pf = *(const bf16x8*)&Pl[w][lr][ks * 32 + lk * 8];
#pragma unroll
        for (int g = 0; g < 8; g++) {
          bf16x8 vf = *(const bf16x8*)(Vt + (size_t)(g * 16 + lr) * 2048 + ks * 32 + lk * 8);
          o[g] = __builtin_amdgcn_mfma_f32_16x16x32_bf16(pf, vf, o[g], 0, 0, 0);
        }
      }
    }
    __syncthreads();  // drains vmcnt -> next K buf staged; all waves done reading cur
  }
  // normalize + store
#pragma unroll
  for (int j = 0; j < 4; j++) {
    float inv = 1.0f / ssum[j];
    int q = q0 + w * 16 + lk * 4 + j;
    ushort_t* orow = AO + (size_t)q * 4096 + h * 128;
#pragma unroll
    for (int g = 0; g < 8; g++) orow[g * 16 + lr] = f2bf(o[g][j] * inv);
  }
}

// ---------- launch ----------
extern "C" void kernel_launch(void* const* d_in, const int* in_sizes, int n_in,
                              void* d_out, int out_size, void* d_ws, size_t ws_size,
                              hipStream_t stream) {
  (void)in_sizes; (void)n_in; (void)out_size; (void)ws_size;
  const float* x    = (const float*)d_in[0];
  const float* wq   = (const float*)d_in[1];
  const float* wk   = (const float*)d_in[2];
  const float* wv   = (const float*)d_in[3];
  const float* wo   = (const float*)d_in[4];
  const float* cosb = (const float*)d_in[5];
  const float* sinb = (const float*)d_in[6];

  char* ws = (char*)d_ws;
  ushort_t* xb  = (ushort_t*)(ws);                        // 16MB; reused as AO
  ushort_t* wT  = (ushort_t*)(ws + ((size_t)16 << 20));   // 48MB; reused as woT
  ushort_t* C1  = (ushort_t*)(ws + ((size_t)64 << 20));   // 24MB
  ushort_t* VT  = (ushort_t*)(ws + ((size_t)88 << 20));   // 4MB
  ushort_t* AO  = xb;
  ushort_t* woT = wT;

  // prep
  cvt_x_kernel<<<4096, 256, 0, stream>>>(x, xb);
  tr_cvt_kernel<<<dim3(64, 64), 256, 0, stream>>>(wq, wT, 4096, 4096);
  tr_cvt_kernel<<<dim3(16, 64), 256, 0, stream>>>(wk, wT + (size_t)4096 * 4096, 4096, 1024);
  tr_cvt_kernel<<<dim3(16, 64), 256, 0, stream>>>(wv, wT + (size_t)5120 * 4096, 4096, 1024);

  // QKV projection
  gemm128_kernel<ushort_t><<<dim3(48, 16), 256, 0, stream>>>(xb, wT, C1, 2048, 6144, 4096, 6144);
  // RoPE on Q,K (Q pre-scaled for log2-domain softmax)
  rope_kernel<<<5120, 256, 0, stream>>>(C1, cosb, sinb);
  // V -> VT
  trv_kernel<<<dim3(16, 32), 256, 0, stream>>>(C1, VT);
  // wo -> woT (wT region is dead after gemm1; safe overlay in stream order)
  tr_cvt_kernel<<<dim3(64, 64), 256, 0, stream>>>(wo, woT, 4096, 4096);
  // attention (8 waves, QBLK=128, K dbuf in LDS, V direct from L2)
  fattn_kernel<<<dim3(32, 16), 512, 0, stream>>>(C1, VT, AO);
  // output projection -> FLOAT out
  gemm128_kernel<float><<<dim3(32, 16), 256, 0, stream>>>(AO, woT, (float*)d_out, 2048, 4096, 4096, 4096);
}

// Round 7
// 489.863 us; speedup vs baseline: 1.0053x; 1.0053x over previous
//
#include <hip/hip_runtime.h>
#include <stdint.h>

typedef unsigned short ushort_t;
typedef short bf16x4 __attribute__((ext_vector_type(4)));
typedef short bf16x8 __attribute__((ext_vector_type(8)));
typedef float f32x4 __attribute__((ext_vector_type(4)));
typedef float f32x16 __attribute__((ext_vector_type(16)));
typedef float f32x4v __attribute__((ext_vector_type(4)));

// ---------- helpers ----------
__device__ __forceinline__ ushort_t f2bf(float f) {
  unsigned int u = __builtin_bit_cast(unsigned int, f);
  u += 0x7fffu + ((u >> 16) & 1u);
  return (ushort_t)(u >> 16);
}
__device__ __forceinline__ float bf2f(ushort_t h) {
  unsigned int u = ((unsigned int)h) << 16;
  return __builtin_bit_cast(float, u);
}
__device__ __forceinline__ float exp2_hw(float x) {
  return __builtin_amdgcn_exp2f(x);  // v_exp_f32: D = 2^S0
}
__device__ __forceinline__ void load_lds16(const void* g, void* l) {
  __builtin_amdgcn_global_load_lds(
      (const __attribute__((address_space(1))) void*)g,
      (__attribute__((address_space(3))) void*)l, 16, 0, 0);
}

// ---------- x fp32 -> bf16 ----------
__global__ __launch_bounds__(256) void cvt_x_kernel(const float* __restrict__ x,
                                                    ushort_t* __restrict__ xb) {
  int i = blockIdx.x * 256 + threadIdx.x;  // each thread: 8 elems
  const f32x4v* xv = (const f32x4v*)x;
  f32x4v a = xv[2 * i], b = xv[2 * i + 1];
  bf16x8 o;
  o[0] = (short)f2bf(a[0]); o[1] = (short)f2bf(a[1]);
  o[2] = (short)f2bf(a[2]); o[3] = (short)f2bf(a[3]);
  o[4] = (short)f2bf(b[0]); o[5] = (short)f2bf(b[1]);
  o[6] = (short)f2bf(b[2]); o[7] = (short)f2bf(b[3]);
  ((bf16x8*)xb)[i] = o;
}

// ---------- weight fp32 [R][C] -> bf16 transposed [C][R] ----------
__global__ __launch_bounds__(256) void tr_cvt_kernel(const float* __restrict__ src,
                                                     ushort_t* __restrict__ dst,
                                                     int R, int C) {
  __shared__ float tile[64][65];
  int r0 = blockIdx.y * 64, c0 = blockIdx.x * 64;
  int t = threadIdx.x;
#pragma unroll
  for (int i = 0; i < 16; i++) {
    int idx = t + i * 256;
    int r = idx >> 6, c = idx & 63;
    tile[r][c] = src[(size_t)(r0 + r) * C + c0 + c];
  }
  __syncthreads();
#pragma unroll
  for (int i = 0; i < 16; i++) {
    int idx = t + i * 256;
    int cr = idx >> 6, cc = idx & 63;
    dst[(size_t)(c0 + cr) * R + r0 + cc] = f2bf(tile[cc][cr]);
  }
}

// ---------- RoPE in-place on C1 (Q cols 0..4095 get pre-scaled, K cols 4096..5119) ----------
// Q is pre-multiplied by 1/sqrt(128)*log2(e) so fattn can use exp2 directly on QK^T.
__global__ __launch_bounds__(256) void rope_kernel(ushort_t* __restrict__ C1,
                                                   const float* __restrict__ cosb,
                                                   const float* __restrict__ sinb) {
  int idx = blockIdx.x * 256 + threadIdx.x;  // 2048 * 640
  int s = idx / 640;
  int col0 = (idx % 640) * 8;
  int i0 = (col0 & 127) >> 1;
  const float qs = (col0 < 4096) ? 0.12753055296570565f : 1.0f;  // scale*log2e
  ushort_t* p = C1 + (size_t)s * 6144 + col0;
  bf16x8 v = *(const bf16x8*)p;
  bf16x8 o;
  const float* cr = cosb + s * 64 + i0;
  const float* sr = sinb + s * 64 + i0;
#pragma unroll
  for (int j = 0; j < 4; j++) {
    float tr = bf2f((ushort_t)v[2 * j]);
    float ti = bf2f((ushort_t)v[2 * j + 1]);
    float c = cr[j], sn = sr[j];
    o[2 * j] = (short)f2bf((tr * c - ti * sn) * qs);
    o[2 * j + 1] = (short)f2bf((tr * sn + ti * c) * qs);
  }
  *(bf16x8*)p = o;
}

// ---------- V part of C1 -> VT [1024][2048] (row = hk*128+d, col = s) ----------
__global__ __launch_bounds__(256) void trv_kernel(const ushort_t* __restrict__ C1,
                                                  ushort_t* __restrict__ VT) {
  __shared__ ushort_t tile[64][65];
  int c0 = blockIdx.x * 64;  // within 1024
  int r0 = blockIdx.y * 64;  // within 2048
  int t = threadIdx.x;
#pragma unroll
  for (int i = 0; i < 16; i++) {
    int idx = t + i * 256;
    int r = idx >> 6, c = idx & 63;
    tile[r][c] = C1[(size_t)(r0 + r) * 6144 + 5120 + c0 + c];
  }
  __syncthreads();
#pragma unroll
  for (int i = 0; i < 16; i++) {
    int idx = t + i * 256;
    int cr = idx >> 6, cc = idx & 63;
    VT[(size_t)(c0 + cr) * 2048 + r0 + cc] = tile[cc][cr];
  }
}

// ---------- GEMM: C[M][ldc] = A[M][K] * BT[N][K]^T  (m97 structure) ----------
template <typename OutT>
__global__ __launch_bounds__(256) void gemm128_kernel(const ushort_t* __restrict__ A,
                                                      const ushort_t* __restrict__ BT,
                                                      OutT* __restrict__ C,
                                                      int M, int N, int K, int ldc) {
  __shared__ ushort_t As[128 * 32];
  __shared__ ushort_t Bs[128 * 32];
  int brow = blockIdx.y * 128, bcol = blockIdx.x * 128;
  int tid = threadIdx.x, w = tid >> 6, lane = tid & 63;
  int wr = w >> 1, wc = w & 1;
  int lr = lane & 15, lk = lane >> 4;
  f32x4 acc[4][4] = {};

  int srow = lane >> 2;
  int scol = (lane & 3) * 8;
  const ushort_t* Ab = A + (size_t)brow * K + scol;
  const ushort_t* Bb = BT + (size_t)bcol * K + scol;

  for (int kt = 0; kt < K; kt += 32) {
#pragma unroll
    for (int i = 0; i < 2; i++) {
      int seg = w * 2 + i;
      int row = seg * 16 + srow;
      load_lds16(Ab + (size_t)row * K + kt, (char*)As + seg * 1024);
      load_lds16(Bb + (size_t)row * K + kt, (char*)Bs + seg * 1024);
    }
    __syncthreads();
    bf16x8 af[4], bfr[4];
#pragma unroll
    for (int m = 0; m < 4; m++)
      af[m] = *(const bf16x8*)&As[(wr * 64 + m * 16 + lr) * 32 + lk * 8];
#pragma unroll
    for (int n = 0; n < 4; n++)
      bfr[n] = *(const bf16x8*)&Bs[(wc * 64 + n * 16 + lr) * 32 + lk * 8];
#pragma unroll
    for (int m = 0; m < 4; m++)
#pragma unroll
      for (int n = 0; n < 4; n++)
        acc[m][n] = __builtin_amdgcn_mfma_f32_16x16x32_bf16(af[m], bfr[n], acc[m][n], 0, 0, 0);
    __syncthreads();
  }
#pragma unroll
  for (int m = 0; m < 4; m++)
#pragma unroll
    for (int n = 0; n < 4; n++) {
      int row = brow + wr * 64 + m * 16 + lk * 4;
      int col = bcol + wc * 64 + n * 16 + lr;
#pragma unroll
      for (int j = 0; j < 4; j++) {
        float v = acc[m][n][j];
        if constexpr (sizeof(OutT) == 2)
          C[(size_t)(row + j) * ldc + col] = (OutT)f2bf(v);
        else
          C[(size_t)(row + j) * ldc + col] = v;
      }
    }
}

// ---------- flash attention: decoupled waves, swapped-operand 32x32 MFMA ----------
// grid (32 heads x 16 qtiles), 256 thr (4 independent waves; NO __syncthreads).
// Each wave owns 32 q-rows. S = mfma(A=K, B=Q) -> S[key][q], q = lane&31:
// softmax state (m, sum) is a per-lane scalar. PV computed transposed:
// O^T = mfma(A=V^T (from VT), B=P) -> O[q][d] with q = lane&31 again, so the
// online rescale is a per-lane scalar multiply. K/V fragments are contiguous
// 16B loads from L2 (XCD-pinned: linear block id % 8 == h % 8 -> ~4MB/XCD).
// P goes through a tiny wave-private LDS tile to reach the B-operand layout.
__global__ __launch_bounds__(256) void fattn_kernel(const ushort_t* __restrict__ C1,
                                                    const ushort_t* __restrict__ VT,
                                                    ushort_t* __restrict__ AO) {
  __shared__ ushort_t Pl[4][32][72];  // [wave][q 0..31][key 0..63 (+8 pad)] = 18KB
  const int h = blockIdx.x, hk = h >> 2;
  const int qt = gridDim.y - 1 - blockIdx.y;  // longest blocks first
  const int tid = threadIdx.x, w = tid >> 6, lane = tid & 63;
  const int lq = lane & 31, hi = lane >> 5;
  const int qw0 = qt * 128 + w * 32;  // wave's first q row
  const int qabs = qw0 + lq;          // this lane's q row

  const ushort_t* Kb = C1 + 4096 + (size_t)hk * 128;  // K rows, stride 6144
  const ushort_t* Vb = VT + (size_t)hk * 128 * 2048;  // V^T rows, stride 2048

  // Q fragments (B-operand): lane holds Q[qabs][slot*16 + hi*8 + 0..7]
  bf16x8 qf[8];
  {
    const ushort_t* qrow = C1 + (size_t)qabs * 6144 + h * 128;
#pragma unroll
    for (int s = 0; s < 8; s++) qf[s] = *(const bf16x8*)(qrow + s * 16 + hi * 8);
  }

  f32x16 ot[4] = {};  // O^T acc: [dblk]; lane holds O[qabs][dblk*32 + crow(r,hi)]
  float mrow = -1e30f, ssum = 0.f;

  const int ktmax = (qw0 + 31) >> 6;
  for (int kt = 0; kt <= ktmax; kt++) {
    // ---- S = K · Q^T  (two 32-key groups) ----
    f32x16 sg[2] = {};
#pragma unroll
    for (int g = 0; g < 2; g++) {
      bf16x8 kfa[8];
      const ushort_t* krow = Kb + (size_t)(kt * 64 + g * 32 + lq) * 6144 + hi * 8;
#pragma unroll
      for (int s = 0; s < 8; s++) kfa[s] = *(const bf16x8*)(krow + s * 16);
#pragma unroll
      for (int s = 0; s < 8; s++)
        sg[g] = __builtin_amdgcn_mfma_f32_32x32x16_bf16(kfa[s], qf[s], sg[g], 0, 0, 0);
    }
    // ---- causal mask (per-lane: key > qabs) ----
    if (kt * 64 + 63 > qw0) {
#pragma unroll
      for (int g = 0; g < 2; g++)
#pragma unroll
        for (int r = 0; r < 16; r++) {
          int key = kt * 64 + g * 32 + (r & 3) + 8 * (r >> 2) + 4 * hi;
          if (key > qabs) sg[g][r] = -1e30f;
        }
    }
    // ---- online softmax, base-2, per-lane scalar state ----
    float pm = -1e30f;
#pragma unroll
    for (int g = 0; g < 2; g++)
#pragma unroll
      for (int r = 0; r < 16; r++) pm = fmaxf(pm, sg[g][r]);
    pm = fmaxf(pm, __shfl_xor(pm, 32));  // other half's 32 keys
    float mnew = fmaxf(mrow, pm);
    float corr = exp2_hw(mrow - mnew);
    mrow = mnew;
    float ps = 0.f;
#pragma unroll
    for (int g = 0; g < 2; g++)
#pragma unroll
      for (int r = 0; r < 16; r++) {
        float e = exp2_hw(sg[g][r] - mnew);
        sg[g][r] = e;
        ps += e;
      }
    ps += __shfl_xor(ps, 32);
    ssum = ssum * corr + ps;
    if (!__all(corr == 1.f)) {  // T13: skip O-rescale when no lane's max grew
#pragma unroll
      for (int d = 0; d < 4; d++)
#pragma unroll
        for (int r = 0; r < 16; r++) ot[d][r] *= corr;
    }
    // ---- P -> wave-private LDS (keys (r&3)+8*(r>>2)+4*hi are 4-consecutive) ----
#pragma unroll
    for (int g = 0; g < 2; g++)
#pragma unroll
      for (int rq = 0; rq < 4; rq++) {
        bf16x4 pk;
#pragma unroll
        for (int j = 0; j < 4; j++) pk[j] = (short)f2bf(sg[g][rq * 4 + j]);
        *(bf16x4*)&Pl[w][lq][g * 32 + rq * 8 + hi * 4] = pk;
      }
    asm volatile("s_waitcnt lgkmcnt(0)" ::: "memory");
    // ---- O^T += V^T · P  (B-operand: lane's own q, keys slot*16 + hi*8) ----
    bf16x8 pf[4];
#pragma unroll
    for (int s = 0; s < 4; s++) pf[s] = *(const bf16x8*)&Pl[w][lq][s * 16 + hi * 8];
#pragma unroll
    for (int d = 0; d < 4; d++) {
      bf16x8 vfa[4];
      const ushort_t* vrow = Vb + (size_t)(d * 32 + lq) * 2048 + kt * 64 + hi * 8;
#pragma unroll
      for (int s = 0; s < 4; s++) vfa[s] = *(const bf16x8*)(vrow + s * 16);
#pragma unroll
      for (int s = 0; s < 4; s++)
        ot[d] = __builtin_amdgcn_mfma_f32_32x32x16_bf16(vfa[s], pf[s], ot[d], 0, 0, 0);
    }
  }
  // ---- normalize + store: lane writes row qabs, d = dblk*32 + (r&3)+8*rq+4*hi ----
  const float inv = 1.0f / ssum;
  ushort_t* orow = AO + (size_t)qabs * 4096 + h * 128;
#pragma unroll
  for (int d = 0; d < 4; d++)
#pragma unroll
    for (int rq = 0; rq < 4; rq++) {
      bf16x4 ok;
#pragma unroll
      for (int j = 0; j < 4; j++) ok[j] = (short)f2bf(ot[d][rq * 4 + j] * inv);
      *(bf16x4*)(orow + d * 32 + rq * 8 + hi * 4) = ok;
    }
}

// ---------- launch ----------
extern "C" void kernel_launch(void* const* d_in, const int* in_sizes, int n_in,
                              void* d_out, int out_size, void* d_ws, size_t ws_size,
                              hipStream_t stream) {
  (void)in_sizes; (void)n_in; (void)out_size; (void)ws_size;
  const float* x    = (const float*)d_in[0];
  const float* wq   = (const float*)d_in[1];
  const float* wk   = (const float*)d_in[2];
  const float* wv   = (const float*)d_in[3];
  const float* wo   = (const float*)d_in[4];
  const float* cosb = (const float*)d_in[5];
  const float* sinb = (const float*)d_in[6];

  char* ws = (char*)d_ws;
  ushort_t* xb  = (ushort_t*)(ws);                        // 16MB; reused as AO
  ushort_t* wT  = (ushort_t*)(ws + ((size_t)16 << 20));   // 48MB; reused as woT
  ushort_t* C1  = (ushort_t*)(ws + ((size_t)64 << 20));   // 24MB
  ushort_t* VT  = (ushort_t*)(ws + ((size_t)88 << 20));   // 4MB
  ushort_t* AO  = xb;
  ushort_t* woT = wT;

  // prep
  cvt_x_kernel<<<4096, 256, 0, stream>>>(x, xb);
  tr_cvt_kernel<<<dim3(64, 64), 256, 0, stream>>>(wq, wT, 4096, 4096);
  tr_cvt_kernel<<<dim3(16, 64), 256, 0, stream>>>(wk, wT + (size_t)4096 * 4096, 4096, 1024);
  tr_cvt_kernel<<<dim3(16, 64), 256, 0, stream>>>(wv, wT + (size_t)5120 * 4096, 4096, 1024);

  // QKV projection
  gemm128_kernel<ushort_t><<<dim3(48, 16), 256, 0, stream>>>(xb, wT, C1, 2048, 6144, 4096, 6144);
  // RoPE on Q,K (Q pre-scaled for log2-domain softmax)
  rope_kernel<<<5120, 256, 0, stream>>>(C1, cosb, sinb);
  // V -> VT
  trv_kernel<<<dim3(16, 32), 256, 0, stream>>>(C1, VT);
  // wo -> woT (wT region is dead after gemm1; safe overlay in stream order)
  tr_cvt_kernel<<<dim3(64, 64), 256, 0, stream>>>(wo, woT, 4096, 4096);
  // attention (4 independent waves/block, no barriers, 32x32 swapped MFMA)
  fattn_kernel<<<dim3(32, 16), 256, 0, stream>>>(C1, VT, AO);
  // output projection -> FLOAT out
  gemm128_kernel<float><<<dim3(32, 16), 256, 0, stream>>>(AO, woT, (float*)d_out, 2048, 4096, 4096, 4096);
}

// Round 8
// 438.001 us; speedup vs baseline: 1.1243x; 1.1184x over previous
//
#include <hip/hip_runtime.h>
#include <stdint.h>

typedef unsigned short ushort_t;
typedef short bf16x4 __attribute__((ext_vector_type(4)));
typedef short bf16x8 __attribute__((ext_vector_type(8)));
typedef float f32x4 __attribute__((ext_vector_type(4)));
typedef float f32x16 __attribute__((ext_vector_type(16)));
typedef float f32x4v __attribute__((ext_vector_type(4)));

// ---------- helpers ----------
__device__ __forceinline__ ushort_t f2bf(float f) {
  unsigned int u = __builtin_bit_cast(unsigned int, f);
  u += 0x7fffu + ((u >> 16) & 1u);
  return (ushort_t)(u >> 16);
}
__device__ __forceinline__ float bf2f(ushort_t h) {
  unsigned int u = ((unsigned int)h) << 16;
  return __builtin_bit_cast(float, u);
}
__device__ __forceinline__ float exp2_hw(float x) {
  return __builtin_amdgcn_exp2f(x);  // v_exp_f32: D = 2^S0
}
__device__ __forceinline__ void load_lds16(const void* g, void* l) {
  __builtin_amdgcn_global_load_lds(
      (const __attribute__((address_space(1))) void*)g,
      (__attribute__((address_space(3))) void*)l, 16, 0, 0);
}

// ---------- x fp32 -> bf16 ----------
__global__ __launch_bounds__(256) void cvt_x_kernel(const float* __restrict__ x,
                                                    ushort_t* __restrict__ xb) {
  int i = blockIdx.x * 256 + threadIdx.x;  // each thread: 8 elems
  const f32x4v* xv = (const f32x4v*)x;
  f32x4v a = xv[2 * i], b = xv[2 * i + 1];
  bf16x8 o;
  o[0] = (short)f2bf(a[0]); o[1] = (short)f2bf(a[1]);
  o[2] = (short)f2bf(a[2]); o[3] = (short)f2bf(a[3]);
  o[4] = (short)f2bf(b[0]); o[5] = (short)f2bf(b[1]);
  o[6] = (short)f2bf(b[2]); o[7] = (short)f2bf(b[3]);
  ((bf16x8*)xb)[i] = o;
}

// ---------- weight fp32 [R][C] -> bf16 transposed [C][R] ----------
__global__ __launch_bounds__(256) void tr_cvt_kernel(const float* __restrict__ src,
                                                     ushort_t* __restrict__ dst,
                                                     int R, int C) {
  __shared__ float tile[64][65];
  int r0 = blockIdx.y * 64, c0 = blockIdx.x * 64;
  int t = threadIdx.x;
#pragma unroll
  for (int i = 0; i < 16; i++) {
    int idx = t + i * 256;
    int r = idx >> 6, c = idx & 63;
    tile[r][c] = src[(size_t)(r0 + r) * C + c0 + c];
  }
  __syncthreads();
#pragma unroll
  for (int i = 0; i < 16; i++) {
    int idx = t + i * 256;
    int cr = idx >> 6, cc = idx & 63;
    dst[(size_t)(c0 + cr) * R + r0 + cc] = f2bf(tile[cc][cr]);
  }
}

// ---------- RoPE in-place on C1 (Q cols 0..4095 pre-scaled by scale*log2e) ----------
__global__ __launch_bounds__(256) void rope_kernel(ushort_t* __restrict__ C1,
                                                   const float* __restrict__ cosb,
                                                   const float* __restrict__ sinb) {
  int idx = blockIdx.x * 256 + threadIdx.x;  // 2048 * 640
  int s = idx / 640;
  int col0 = (idx % 640) * 8;
  int i0 = (col0 & 127) >> 1;
  const float qs = (col0 < 4096) ? 0.12753055296570565f : 1.0f;  // scale*log2e
  ushort_t* p = C1 + (size_t)s * 6144 + col0;
  bf16x8 v = *(const bf16x8*)p;
  bf16x8 o;
  const float* cr = cosb + s * 64 + i0;
  const float* sr = sinb + s * 64 + i0;
#pragma unroll
  for (int j = 0; j < 4; j++) {
    float tr = bf2f((ushort_t)v[2 * j]);
    float ti = bf2f((ushort_t)v[2 * j + 1]);
    float c = cr[j], sn = sr[j];
    o[2 * j] = (short)f2bf((tr * c - ti * sn) * qs);
    o[2 * j + 1] = (short)f2bf((tr * sn + ti * c) * qs);
  }
  *(bf16x8*)p = o;
}

// ---------- V part of C1 -> VT [1024][2048] (row = hk*128+d, col = s) ----------
__global__ __launch_bounds__(256) void trv_kernel(const ushort_t* __restrict__ C1,
                                                  ushort_t* __restrict__ VT) {
  __shared__ ushort_t tile[64][65];
  int c0 = blockIdx.x * 64;  // within 1024
  int r0 = blockIdx.y * 64;  // within 2048
  int t = threadIdx.x;
#pragma unroll
  for (int i = 0; i < 16; i++) {
    int idx = t + i * 256;
    int r = idx >> 6, c = idx & 63;
    tile[r][c] = C1[(size_t)(r0 + r) * 6144 + 5120 + c0 + c];
  }
  __syncthreads();
#pragma unroll
  for (int i = 0; i < 16; i++) {
    int idx = t + i * 256;
    int cr = idx >> 6, cc = idx & 63;
    VT[(size_t)(c0 + cr) * 2048 + r0 + cc] = tile[cc][cr];
  }
}

// ---------- GEMM: C[M][ldc] = A[M][K] * BT[N][K]^T  (m97 structure) ----------
template <typename OutT>
__global__ __launch_bounds__(256) void gemm128_kernel(const ushort_t* __restrict__ A,
                                                      const ushort_t* __restrict__ BT,
                                                      OutT* __restrict__ C,
                                                      int M, int N, int K, int ldc) {
  __shared__ ushort_t As[128 * 32];
  __shared__ ushort_t Bs[128 * 32];
  int brow = blockIdx.y * 128, bcol = blockIdx.x * 128;
  int tid = threadIdx.x, w = tid >> 6, lane = tid & 63;
  int wr = w >> 1, wc = w & 1;
  int lr = lane & 15, lk = lane >> 4;
  f32x4 acc[4][4] = {};

  int srow = lane >> 2;
  int scol = (lane & 3) * 8;
  const ushort_t* Ab = A + (size_t)brow * K + scol;
  const ushort_t* Bb = BT + (size_t)bcol * K + scol;

  for (int kt = 0; kt < K; kt += 32) {
#pragma unroll
    for (int i = 0; i < 2; i++) {
      int seg = w * 2 + i;
      int row = seg * 16 + srow;
      load_lds16(Ab + (size_t)row * K + kt, (char*)As + seg * 1024);
      load_lds16(Bb + (size_t)row * K + kt, (char*)Bs + seg * 1024);
    }
    __syncthreads();
    bf16x8 af[4], bfr[4];
#pragma unroll
    for (int m = 0; m < 4; m++)
      af[m] = *(const bf16x8*)&As[(wr * 64 + m * 16 + lr) * 32 + lk * 8];
#pragma unroll
    for (int n = 0; n < 4; n++)
      bfr[n] = *(const bf16x8*)&Bs[(wc * 64 + n * 16 + lr) * 32 + lk * 8];
#pragma unroll
    for (int m = 0; m < 4; m++)
#pragma unroll
      for (int n = 0; n < 4; n++)
        acc[m][n] = __builtin_amdgcn_mfma_f32_16x16x32_bf16(af[m], bfr[n], acc[m][n], 0, 0, 0);
    __syncthreads();
  }
#pragma unroll
  for (int m = 0; m < 4; m++)
#pragma unroll
    for (int n = 0; n < 4; n++) {
      int row = brow + wr * 64 + m * 16 + lk * 4;
      int col = bcol + wc * 64 + n * 16 + lr;
#pragma unroll
      for (int j = 0; j < 4; j++) {
        float v = acc[m][n][j];
        if constexpr (sizeof(OutT) == 2)
          C[(size_t)(row + j) * ldc + col] = (OutT)f2bf(v);
        else
          C[(size_t)(row + j) * ldc + col] = v;
      }
    }
}

// ---------- gemmS: P[tile] = exp2(Q K^T) causal, materialized bf16 ----------
// grid (136 tiles, 32 heads). Causal-packed: head stride 136 tiles of 128x128,
// tile (rt,ct) at index tri(rt)+ct. No max subtraction (|s| <= ~12 << 127).
__global__ __launch_bounds__(256) void gemmS_kernel(const ushort_t* __restrict__ C1,
                                                    ushort_t* __restrict__ P) {
  int rem = blockIdx.x, rt = 0;
  while (rem > rt) { rem -= (rt + 1); rt++; }
  const int ct = rem;
  const int h = blockIdx.y, hk = h >> 2;

  __shared__ ushort_t As[128 * 32];
  __shared__ ushort_t Bs[128 * 32];
  int tid = threadIdx.x, w = tid >> 6, lane = tid & 63;
  int wr = w >> 1, wc = w & 1;
  int lr = lane & 15, lk = lane >> 4;
  f32x4 acc[4][4] = {};
  int srow = lane >> 2;
  int scol = (lane & 3) * 8;
  const ushort_t* Ab = C1 + (size_t)(rt * 128) * 6144 + h * 128 + scol;         // Q
  const ushort_t* Bb = C1 + (size_t)(ct * 128) * 6144 + 4096 + hk * 128 + scol; // K

  for (int kt = 0; kt < 128; kt += 32) {
#pragma unroll
    for (int i = 0; i < 2; i++) {
      int seg = w * 2 + i;
      int row = seg * 16 + srow;
      load_lds16(Ab + (size_t)row * 6144 + kt, (char*)As + seg * 1024);
      load_lds16(Bb + (size_t)row * 6144 + kt, (char*)Bs + seg * 1024);
    }
    __syncthreads();
    bf16x8 af[4], bfr[4];
#pragma unroll
    for (int m = 0; m < 4; m++)
      af[m] = *(const bf16x8*)&As[(wr * 64 + m * 16 + lr) * 32 + lk * 8];
#pragma unroll
    for (int n = 0; n < 4; n++)
      bfr[n] = *(const bf16x8*)&Bs[(wc * 64 + n * 16 + lr) * 32 + lk * 8];
#pragma unroll
    for (int m = 0; m < 4; m++)
#pragma unroll
      for (int n = 0; n < 4; n++)
        acc[m][n] = __builtin_amdgcn_mfma_f32_16x16x32_bf16(af[m], bfr[n], acc[m][n], 0, 0, 0);
    __syncthreads();
  }
  ushort_t* Pt = P + ((size_t)h * 136 + (size_t)(rt * (rt + 1) / 2) + ct) * 16384;
  const bool diag = (rt == ct);
#pragma unroll
  for (int m = 0; m < 4; m++)
#pragma unroll
    for (int n = 0; n < 4; n++) {
      int row = wr * 64 + m * 16 + lk * 4;
      int col = wc * 64 + n * 16 + lr;
#pragma unroll
      for (int j = 0; j < 4; j++) {
        float v = exp2_hw(acc[m][n][j]);
        if (diag && col > row + j) v = 0.f;
        Pt[(row + j) * 128 + col] = f2bf(v);
      }
    }
}

// ---------- rowsum: inv[h][r] = 1 / sum_k P[h][r][k] ----------
// one wave per row; grid 16384 x 256 thr (4 waves).
__global__ __launch_bounds__(256) void rowsum_kernel(const ushort_t* __restrict__ P,
                                                     float* __restrict__ inv) {
  int row = blockIdx.x * 4 + (threadIdx.x >> 6);  // 0..65535
  int lane = threadIdx.x & 63;
  int h = row >> 11, r = row & 2047;
  int rt = r >> 7, rr = r & 127;
  const ushort_t* Ph = P + ((size_t)h * 136 + (size_t)(rt * (rt + 1) / 2)) * 16384 + rr * 128;
  float s = 0.f;
  for (int ct0 = 0; ct0 <= rt; ct0 += 4) {
    int ct = ct0 + (lane >> 4);
    if (ct <= rt) {
      bf16x8 v = *(const bf16x8*)(Ph + (size_t)ct * 16384 + (lane & 15) * 8);
#pragma unroll
      for (int j = 0; j < 8; j++) s += bf2f((ushort_t)v[j]);
    }
  }
#pragma unroll
  for (int off = 1; off < 64; off <<= 1) s += __shfl_xor(s, off, 64);
  if (lane == 0) inv[row] = 1.0f / s;
}

// ---------- gemmPV: AO[rt-tile] = (P * V) * inv ----------
// grid (32 heads, 16): rt = 15 - blockIdx.y so block pairs (id, id+256) get
// rt and rt-8 -> per-CU load ~balanced. A = packed P, BT = VT rows.
__global__ __launch_bounds__(256) void gemmPV_kernel(const ushort_t* __restrict__ P,
                                                     const ushort_t* __restrict__ VT,
                                                     const float* __restrict__ inv,
                                                     ushort_t* __restrict__ AO) {
  const int h = blockIdx.x, hk = h >> 2;
  const int rt = 15 - (int)blockIdx.y;

  __shared__ ushort_t As[128 * 32];
  __shared__ ushort_t Bs[128 * 32];
  int tid = threadIdx.x, w = tid >> 6, lane = tid & 63;
  int wr = w >> 1, wc = w & 1;
  int lr = lane & 15, lk = lane >> 4;
  f32x4 acc[4][4] = {};
  int srow = lane >> 2;
  int scol = (lane & 3) * 8;
  const ushort_t* Ph = P + ((size_t)h * 136 + (size_t)(rt * (rt + 1) / 2)) * 16384;
  const ushort_t* Vh = VT + (size_t)hk * 128 * 2048;

  const int nks = (rt + 1) * 4;
  for (int ks = 0; ks < nks; ks++) {
    int k0 = ks * 32;
    int ctk = k0 >> 7, kin = k0 & 127;
#pragma unroll
    for (int i = 0; i < 2; i++) {
      int seg = w * 2 + i;
      int row = seg * 16 + srow;
      load_lds16(Ph + (size_t)ctk * 16384 + (size_t)row * 128 + kin + scol,
                 (char*)As + seg * 1024);
      load_lds16(Vh + (size_t)row * 2048 + k0 + scol, (char*)Bs + seg * 1024);
    }
    __syncthreads();
    bf16x8 af[4], bfr[4];
#pragma unroll
    for (int m = 0; m < 4; m++)
      af[m] = *(const bf16x8*)&As[(wr * 64 + m * 16 + lr) * 32 + lk * 8];
#pragma unroll
    for (int n = 0; n < 4; n++)
      bfr[n] = *(const bf16x8*)&Bs[(wc * 64 + n * 16 + lr) * 32 + lk * 8];
#pragma unroll
    for (int m = 0; m < 4; m++)
#pragma unroll
      for (int n = 0; n < 4; n++)
        acc[m][n] = __builtin_amdgcn_mfma_f32_16x16x32_bf16(af[m], bfr[n], acc[m][n], 0, 0, 0);
    __syncthreads();
  }
  const int q0 = rt * 128;
#pragma unroll
  for (int m = 0; m < 4; m++)
#pragma unroll
    for (int n = 0; n < 4; n++) {
      int row = wr * 64 + m * 16 + lk * 4;
      int col = wc * 64 + n * 16 + lr;
#pragma unroll
      for (int j = 0; j < 4; j++) {
        float v = acc[m][n][j] * inv[h * 2048 + q0 + row + j];
        AO[(size_t)(q0 + row + j) * 4096 + h * 128 + col] = f2bf(v);
      }
    }
}

// ---------- flash attention (fallback when workspace too small) ----------
__global__ __launch_bounds__(256) void fattn_kernel(const ushort_t* __restrict__ C1,
                                                    const ushort_t* __restrict__ VT,
                                                    ushort_t* __restrict__ AO) {
  __shared__ ushort_t Pl[4][32][72];
  const int h = blockIdx.x, hk = h >> 2;
  const int qt = gridDim.y - 1 - blockIdx.y;
  const int tid = threadIdx.x, w = tid >> 6, lane = tid & 63;
  const int lq = lane & 31, hi = lane >> 5;
  const int qw0 = qt * 128 + w * 32;
  const int qabs = qw0 + lq;

  const ushort_t* Kb = C1 + 4096 + (size_t)hk * 128;
  const ushort_t* Vb = VT + (size_t)hk * 128 * 2048;

  bf16x8 qf[8];
  {
    const ushort_t* qrow = C1 + (size_t)qabs * 6144 + h * 128;
#pragma unroll
    for (int s = 0; s < 8; s++) qf[s] = *(const bf16x8*)(qrow + s * 16 + hi * 8);
  }
  f32x16 ot[4] = {};
  float mrow = -1e30f, ssum = 0.f;

  const int ktmax = (qw0 + 31) >> 6;
  for (int kt = 0; kt <= ktmax; kt++) {
    f32x16 sg[2] = {};
#pragma unroll
    for (int g = 0; g < 2; g++) {
      bf16x8 kfa[8];
      const ushort_t* krow = Kb + (size_t)(kt * 64 + g * 32 + lq) * 6144 + hi * 8;
#pragma unroll
      for (int s = 0; s < 8; s++) kfa[s] = *(const bf16x8*)(krow + s * 16);
#pragma unroll
      for (int s = 0; s < 8; s++)
        sg[g] = __builtin_amdgcn_mfma_f32_32x32x16_bf16(kfa[s], qf[s], sg[g], 0, 0, 0);
    }
    if (kt * 64 + 63 > qw0) {
#pragma unroll
      for (int g = 0; g < 2; g++)
#pragma unroll
        for (int r = 0; r < 16; r++) {
          int key = kt * 64 + g * 32 + (r & 3) + 8 * (r >> 2) + 4 * hi;
          if (key > qabs) sg[g][r] = -1e30f;
        }
    }
    float pm = -1e30f;
#pragma unroll
    for (int g = 0; g < 2; g++)
#pragma unroll
      for (int r = 0; r < 16; r++) pm = fmaxf(pm, sg[g][r]);
    pm = fmaxf(pm, __shfl_xor(pm, 32));
    float mnew = fmaxf(mrow, pm);
    float corr = exp2_hw(mrow - mnew);
    mrow = mnew;
    float ps = 0.f;
#pragma unroll
    for (int g = 0; g < 2; g++)
#pragma unroll
      for (int r = 0; r < 16; r++) {
        float e = exp2_hw(sg[g][r] - mnew);
        sg[g][r] = e;
        ps += e;
      }
    ps += __shfl_xor(ps, 32);
    ssum = ssum * corr + ps;
    if (!__all(corr == 1.f)) {
#pragma unroll
      for (int d = 0; d < 4; d++)
#pragma unroll
        for (int r = 0; r < 16; r++) ot[d][r] *= corr;
    }
#pragma unroll
    for (int g = 0; g < 2; g++)
#pragma unroll
      for (int rq = 0; rq < 4; rq++) {
        bf16x4 pk;
#pragma unroll
        for (int j = 0; j < 4; j++) pk[j] = (short)f2bf(sg[g][rq * 4 + j]);
        *(bf16x4*)&Pl[w][lq][g * 32 + rq * 8 + hi * 4] = pk;
      }
    asm volatile("s_waitcnt lgkmcnt(0)" ::: "memory");
    bf16x8 pf[4];
#pragma unroll
    for (int s = 0; s < 4; s++) pf[s] = *(const bf16x8*)&Pl[w][lq][s * 16 + hi * 8];
#pragma unroll
    for (int d = 0; d < 4; d++) {
      bf16x8 vfa[4];
      const ushort_t* vrow = Vb + (size_t)(d * 32 + lq) * 2048 + kt * 64 + hi * 8;
#pragma unroll
      for (int s = 0; s < 4; s++) vfa[s] = *(const bf16x8*)(vrow + s * 16);
#pragma unroll
      for (int s = 0; s < 4; s++)
        ot[d] = __builtin_amdgcn_mfma_f32_32x32x16_bf16(vfa[s], pf[s], ot[d], 0, 0, 0);
    }
  }
  const float inv = 1.0f / ssum;
  ushort_t* orow = AO + (size_t)qabs * 4096 + h * 128;
#pragma unroll
  for (int d = 0; d < 4; d++)
#pragma unroll
    for (int rq = 0; rq < 4; rq++) {
      bf16x4 ok;
#pragma unroll
      for (int j = 0; j < 4; j++) ok[j] = (short)f2bf(ot[d][rq * 4 + j] * inv);
      *(bf16x4*)(orow + d * 32 + rq * 8 + hi * 4) = ok;
    }
}

// ---------- launch ----------
extern "C" void kernel_launch(void* const* d_in, const int* in_sizes, int n_in,
                              void* d_out, int out_size, void* d_ws, size_t ws_size,
                              hipStream_t stream) {
  (void)in_sizes; (void)n_in; (void)out_size;
  const float* x    = (const float*)d_in[0];
  const float* wq   = (const float*)d_in[1];
  const float* wk   = (const float*)d_in[2];
  const float* wv   = (const float*)d_in[3];
  const float* wo   = (const float*)d_in[4];
  const float* cosb = (const float*)d_in[5];
  const float* sinb = (const float*)d_in[6];

  char* ws = (char*)d_ws;
  const bool fast = ws_size >= (215ull << 20);

  if (fast) {
    // layout (MiB): C1[0,24) VT[24,28) woT[28,60) xb[60,76) wT[76,124)
    //               P[60,196) (xb+wT dead after gemm1)  AO[196,212) inv[212,213)
    ushort_t* C1  = (ushort_t*)(ws);
    ushort_t* VT  = (ushort_t*)(ws + ((size_t)24 << 20));
    ushort_t* woT = (ushort_t*)(ws + ((size_t)28 << 20));
    ushort_t* xb  = (ushort_t*)(ws + ((size_t)60 << 20));
    ushort_t* wT  = (ushort_t*)(ws + ((size_t)76 << 20));
    ushort_t* P   = (ushort_t*)(ws + ((size_t)60 << 20));
    ushort_t* AO  = (ushort_t*)(ws + ((size_t)196 << 20));
    float*    inv = (float*)(ws + ((size_t)212 << 20));

    cvt_x_kernel<<<4096, 256, 0, stream>>>(x, xb);
    tr_cvt_kernel<<<dim3(64, 64), 256, 0, stream>>>(wq, wT, 4096, 4096);
    tr_cvt_kernel<<<dim3(16, 64), 256, 0, stream>>>(wk, wT + (size_t)4096 * 4096, 4096, 1024);
    tr_cvt_kernel<<<dim3(16, 64), 256, 0, stream>>>(wv, wT + (size_t)5120 * 4096, 4096, 1024);
    tr_cvt_kernel<<<dim3(64, 64), 256, 0, stream>>>(wo, woT, 4096, 4096);

    gemm128_kernel<ushort_t><<<dim3(48, 16), 256, 0, stream>>>(xb, wT, C1, 2048, 6144, 4096, 6144);
    rope_kernel<<<5120, 256, 0, stream>>>(C1, cosb, sinb);
    trv_kernel<<<dim3(16, 32), 256, 0, stream>>>(C1, VT);

    gemmS_kernel<<<dim3(136, 32), 256, 0, stream>>>(C1, P);
    rowsum_kernel<<<16384, 256, 0, stream>>>(P, inv);
    gemmPV_kernel<<<dim3(32, 16), 256, 0, stream>>>(P, VT, inv, AO);

    gemm128_kernel<float><<<dim3(32, 16), 256, 0, stream>>>(AO, woT, (float*)d_out, 2048, 4096, 4096, 4096);
  } else {
    // proven 92MiB layout + R7 fattn
    ushort_t* xb  = (ushort_t*)(ws);
    ushort_t* wT  = (ushort_t*)(ws + ((size_t)16 << 20));
    ushort_t* C1  = (ushort_t*)(ws + ((size_t)64 << 20));
    ushort_t* VT  = (ushort_t*)(ws + ((size_t)88 << 20));
    ushort_t* AO  = xb;
    ushort_t* woT = wT;

    cvt_x_kernel<<<4096, 256, 0, stream>>>(x, xb);
    tr_cvt_kernel<<<dim3(64, 64), 256, 0, stream>>>(wq, wT, 4096, 4096);
    tr_cvt_kernel<<<dim3(16, 64), 256, 0, stream>>>(wk, wT + (size_t)4096 * 4096, 4096, 1024);
    tr_cvt_kernel<<<dim3(16, 64), 256, 0, stream>>>(wv, wT + (size_t)5120 * 4096, 4096, 1024);
    gemm128_kernel<ushort_t><<<dim3(48, 16), 256, 0, stream>>>(xb, wT, C1, 2048, 6144, 4096, 6144);
    rope_kernel<<<5120, 256, 0, stream>>>(C1, cosb, sinb);
    trv_kernel<<<dim3(16, 32), 256, 0, stream>>>(C1, VT);
    tr_cvt_kernel<<<dim3(64, 64), 256, 0, stream>>>(wo, woT, 4096, 4096);
    fattn_kernel<<<dim3(32, 16), 256, 0, stream>>>(C1, VT, AO);
    gemm128_kernel<float><<<dim3(32, 16), 256, 0, stream>>>(AO, woT, (float*)d_out, 2048, 4096, 4096, 4096);
  }
}